// Round 11
// baseline (274.062 us; speedup 1.0000x reference)
//
#include <hip/hip_runtime.h>
#include <hip/hip_bf16.h>
#include <math.h>

constexpr int B_   = 8;
constexpr int N_   = 2048;
constexpr int FIN  = 256;
constexpr int FOUT = 128;

constexpr int CH  = 512;          // KB K-chunk length
constexpr int NCH = N_ / CH;      // 4 chunks
constexpr int PR  = 520;          // 16B-aligned row stride (1040 B); R8 showed
                                  // non-multiple-of-8 pad splits ds_read_b128
constexpr int KR  = 32;           // kb rows per block (R9 win: halves Whf L2)
constexpr int XR  = FIN + 8;      // 264 shorts per xs row (pad)
constexpr int TR  = 40;           // ka transpose-tile row stride (32 j + 8 pad)

typedef __attribute__((ext_vector_type(8))) short bf16x8;
typedef __attribute__((ext_vector_type(4))) float f32x4;
typedef __attribute__((ext_vector_type(4))) int   i32x4;

static __device__ __forceinline__ unsigned short f2bf(float f) {
    __hip_bfloat16 h = __float2bfloat16(f);
    return *reinterpret_cast<unsigned short*>(&h);
}
static __device__ __forceinline__ i32x4 ntload4(const int* p) {
    return __builtin_nontemporal_load((const i32x4*)p);
}

// ---------------------------------------------------------------------------
// K0: Wt[n][k] = bf16(W[k][n])  (dim-major weight, 64 KB). Tiny (~3 us).
// ---------------------------------------------------------------------------
__global__ __launch_bounds__(256) void k0_wt(const float* __restrict__ W,
                                             unsigned short* __restrict__ Wt) {
    Wt[blockIdx.x * FIN + threadIdx.x] = f2bf(W[threadIdx.x * FOUT + blockIdx.x]);
}

// ---------------------------------------------------------------------------
// KF: fused ka (Wh GEMM -> fragment-major Whf + f1/f2) AND adj->bitmask pack
// via block-role split (R7; at its ~210 MB HBM roofline, ~31 us). UNCHANGED.
// ---------------------------------------------------------------------------
__global__ __launch_bounds__(256) void kf_ka_pack(
        const float* __restrict__ x,
        const unsigned short* __restrict__ Wt,
        const float* __restrict__ a,
        const int* __restrict__ adj,
        unsigned short* __restrict__ Whf,
        float* __restrict__ f1,
        float* __restrict__ f2,
        unsigned long long* __restrict__ maskW) {
    __shared__ unsigned short xs[32 * XR];   // 16.5 KB; reused as T[128][TR]
    __shared__ float as[2 * FOUT];           // 1 KB
    __shared__ float fred[2][4][32];         // 1 KB

    const int beta = blockIdx.x;
    const int tid  = threadIdx.x;

    if (beta % 5 != 0) {
        // ================= pack role (2048 blocks) =================
        // bit l of maskW[4g+q] = (adj[256g + 4l + q] > 0)   (verified R4+)
        const int pid  = beta - beta / 5 - 1;       // 0..2047
        const int lane = tid & 63, wv = tid >> 6;
        const int gbase = pid * 64 + wv * 16;       // 131072 groups total
        for (int t0 = 0; t0 < 16; t0 += 4) {
            i32x4 vv[4];
#pragma unroll
            for (int u = 0; u < 4; ++u)
                vv[u] = ntload4(adj + (size_t)(gbase + t0 + u) * 256 + 4 * lane);
#pragma unroll
            for (int u = 0; u < 4; ++u) {
                const int g = gbase + t0 + u;
                unsigned long long b0 = __ballot(vv[u][0] > 0);
                unsigned long long b1 = __ballot(vv[u][1] > 0);
                unsigned long long b2 = __ballot(vv[u][2] > 0);
                unsigned long long b3 = __ballot(vv[u][3] > 0);
                if (lane < 4) {
                    unsigned long long w = (lane == 0) ? b0
                                         : (lane == 1) ? b1
                                         : (lane == 2) ? b2 : b3;
                    maskW[(size_t)4 * g + lane] = w;
                }
            }
        }
        return;
    }

    // ================= ka role (512 blocks) =================
    // Whf fragment-major: element (d = nt*16+n16, k = K8*8+j) at
    // ((b*8+nt)*256 + K8)*128 + n16*8 + j   (verified R5+).
    const int j0 = (beta / 5) * 32;          // global flat row base
    const int b  = j0 >> 11;
    const int jb = j0 & (N_ - 1);

    if (tid < 2 * FOUT) as[tid] = a[tid];
    {   // stage 32 x-rows (fp32 -> bf16), coalesced 32 KB read
        const float4* xsrc = (const float4*)(x + (size_t)j0 * FIN);
#pragma unroll
        for (int t = 0; t < 8; ++t) {
            const int idx = tid + t * 256;
            float4 v = xsrc[idx];
            const int row = idx >> 6, c4 = idx & 63;
            ushort4 u;
            u.x = f2bf(v.x); u.y = f2bf(v.y); u.z = f2bf(v.z); u.w = f2bf(v.w);
            *(ushort4*)&xs[row * XR + c4 * 4] = u;
        }
    }
    __syncthreads();

    const int wave = tid >> 6, lane = tid & 63;
    const int quad = lane >> 4, l16 = lane & 15;

    f32x4 acc[2][2];  // [a-tile(d)][n-tile(j)]
#pragma unroll
    for (int aa = 0; aa < 2; ++aa)
#pragma unroll
        for (int nn = 0; nn < 2; ++nn) acc[aa][nn] = {0.f, 0.f, 0.f, 0.f};

    const unsigned short* wtA0 = Wt + (size_t)(32 * wave + l16) * FIN;
    const unsigned short* wtA1 = wtA0 + 16 * FIN;
#pragma unroll
    for (int ks = 0; ks < FIN / 32; ++ks) {
        const int kof = ks * 32 + quad * 8;
        bf16x8 af0 = *(const bf16x8*)&wtA0[kof];
        bf16x8 af1 = *(const bf16x8*)&wtA1[kof];
        bf16x8 bf0 = *(const bf16x8*)&xs[l16 * XR + kof];
        bf16x8 bf1 = *(const bf16x8*)&xs[(16 + l16) * XR + kof];
        acc[0][0] = __builtin_amdgcn_mfma_f32_16x16x32_bf16(af0, bf0, acc[0][0], 0, 0, 0);
        acc[0][1] = __builtin_amdgcn_mfma_f32_16x16x32_bf16(af0, bf1, acc[0][1], 0, 0, 0);
        acc[1][0] = __builtin_amdgcn_mfma_f32_16x16x32_bf16(af1, bf0, acc[1][0], 0, 0, 0);
        acc[1][1] = __builtin_amdgcn_mfma_f32_16x16x32_bf16(af1, bf1, acc[1][1], 0, 0, 0);
    }
    __syncthreads();   // xs dead; safe to reuse as transpose tile T

    unsigned short* T = xs;   // [128][TR]
    float pf[2][2] = {{0.f, 0.f}, {0.f, 0.f}};  // [f1/f2][n-tile]
#pragma unroll
    for (int aa = 0; aa < 2; ++aa)
#pragma unroll
        for (int nn = 0; nn < 2; ++nn)
#pragma unroll
            for (int r = 0; r < 4; ++r) {
                const int d = 32 * wave + 16 * aa + 4 * quad + r;
                const float v = acc[aa][nn][r];
                T[d * TR + nn * 16 + l16] = f2bf(v);
                pf[0][nn] += v * as[d];
                pf[1][nn] += v * as[FOUT + d];
            }
#pragma unroll
    for (int ff = 0; ff < 2; ++ff)
#pragma unroll
        for (int nn = 0; nn < 2; ++nn) {
            float v = pf[ff][nn];
            v += __shfl_xor(v, 16);
            v += __shfl_xor(v, 32);
            pf[ff][nn] = v;
        }
    if (quad == 0) {
#pragma unroll
        for (int ff = 0; ff < 2; ++ff)
#pragma unroll
            for (int nn = 0; nn < 2; ++nn)
                fred[ff][wave][nn * 16 + l16] = pf[ff][nn];
    }
    __syncthreads();

    // ---- Epilogue: write fragment-major Whf from the T tile ----
    unsigned short* dstW = Whf + (size_t)(b * 8) * 256 * 128;  // batch base
    const int jb8 = jb >> 3;
#pragma unroll
    for (int it = 0; it < 2; ++it) {
        const int i   = it * 256 + tid;
        const int n16 = i & 15, q = (i >> 4) & 3, nt = i >> 6;
        bf16x8 v = *(const bf16x8*)&T[(nt * 16 + n16) * TR + q * 8];
        *(bf16x8*)&dstW[((size_t)nt * 256 + jb8 + q) * 128 + n16 * 8] = v;
    }
    if (tid < 64) {
        const int ff = tid >> 5, j32 = tid & 31;
        const float s = fred[ff][0][j32] + fred[ff][1][j32] +
                        fred[ff][2][j32] + fred[ff][3][j32];
        (ff ? f2 : f1)[(size_t)b * N_ + jb + j32] = s;
    }
}

// ---------------------------------------------------------------------------
// KB: fused masked softmax + P@Wh (MFMA) + ELU.
// R11 = resubmit of R10 (container failed twice; hypothesis untested):
// R9 (KR=32, PR=520, (512,4)) + forced Whf register prefetch:
// per chunk, all 16 contiguous B-fragment loads are issued FIRST (oldest
// vmem), pinned register-resident via asm keep-alives, and fenced with
// sched_barrier(0); PROCESS(c+1)'s loads are younger, so the MFMA loop's
// br waits never drain them, and the ~300-500cy L2 latency of br hides
// under PROCESS's exp chain. (The R3 pin mechanism, proven to materialize
// -- re-aimed now that the L2-sector scatter bound is gone.)
// Values and accumulation order unchanged -> absmax 0.0625.
// ---------------------------------------------------------------------------
__global__ __launch_bounds__(512, 4) void kb_attn(const unsigned long long* __restrict__ maskW,
                                                  const unsigned short* __restrict__ Whf,
                                                  const float* __restrict__ f1,
                                                  const float* __restrict__ f2,
                                                  float* __restrict__ out) {
    __shared__ unsigned short p[2][KR * PR];  // 66.6 KB
    __shared__ float rsum[KR];

    const int tid  = threadIdx.x;
    const int b    = blockIdx.x & 7;          // XCD-pinned batch
    const int i0   = (blockIdx.x >> 3) * KR;  // 32-row tile
    const int wave = tid >> 6, lane = tid & 63;  // wave 0..7
    const int quad = lane >> 4, l16 = lane & 15;

    const f32x4* f2b4 = (const f32x4*)(f2 + (size_t)b * N_);

    float f1r[4], s_run[4];
#pragma unroll
    for (int rr = 0; rr < 4; ++rr) {
        f1r[rr]   = f1[(size_t)b * N_ + i0 + wave * 4 + rr];
        s_run[rr] = 0.f;
    }

    f32x4 acc0 = {0.f, 0.f, 0.f, 0.f};   // rows  0..15 of the tile
    f32x4 acc1 = {0.f, 0.f, 0.f, 0.f};   // rows 16..31 of the tile
    // fragment-major base for this wave's n-tile (nt = wave):
    // element (c,ks): offset = ((b*8+wave)*256 + c*64 + ks*4 + quad)*128
    //                          + l16*8
    const unsigned short* wAll =
        Whf + ((size_t)(b * 8 + wave) * 256) * 128 + quad * 128 + l16 * 8;

    // Consume chunk c: leaky-relu, mask-by-bit, exp, rowsum, pack->LDS.
    auto PROCESS = [&](int c) {
        unsigned short* pb = &p[c & 1][0];
        const f32x4 fva = f2b4[c * (CH / 4) + lane];
        const f32x4 fvb = f2b4[c * (CH / 4) + 64 + lane];
#pragma unroll
        for (int rr = 0; rr < 4; ++rr) {
            const int ti = wave * 4 + rr;
            const float f1i = f1r[rr];
            const size_t gbase =
                (((size_t)b * N_ + (size_t)(i0 + ti)) * N_ + (size_t)c * CH) >> 8;
            const unsigned long long* mw = maskW + 4 * gbase;   // wave-uniform
            const unsigned long long m00 = mw[0], m01 = mw[1];
            const unsigned long long m02 = mw[2], m03 = mw[3];
            const unsigned long long m10 = mw[4], m11 = mw[5];
            const unsigned long long m12 = mw[6], m13 = mw[7];

            float e[8];
            e[0] = f1i + fva[0]; e[1] = f1i + fva[1];
            e[2] = f1i + fva[2]; e[3] = f1i + fva[3];
            e[4] = f1i + fvb[0]; e[5] = f1i + fvb[1];
            e[6] = f1i + fvb[2]; e[7] = f1i + fvb[3];
#pragma unroll
            for (int q = 0; q < 8; ++q) e[q] = (e[q] >= 0.f) ? e[q] : 2.f * e[q];

            float pv[8];
            pv[0] = ((m00 >> lane) & 1ull) ? __expf(e[0]) : 0.f;
            pv[1] = ((m01 >> lane) & 1ull) ? __expf(e[1]) : 0.f;
            pv[2] = ((m02 >> lane) & 1ull) ? __expf(e[2]) : 0.f;
            pv[3] = ((m03 >> lane) & 1ull) ? __expf(e[3]) : 0.f;
            pv[4] = ((m10 >> lane) & 1ull) ? __expf(e[4]) : 0.f;
            pv[5] = ((m11 >> lane) & 1ull) ? __expf(e[5]) : 0.f;
            pv[6] = ((m12 >> lane) & 1ull) ? __expf(e[6]) : 0.f;
            pv[7] = ((m13 >> lane) & 1ull) ? __expf(e[7]) : 0.f;

            s_run[rr] += ((pv[0] + pv[1]) + (pv[2] + pv[3])) +
                         ((pv[4] + pv[5]) + (pv[6] + pv[7]));

            ushort4 u0, u1;
            u0.x = f2bf(pv[0]); u0.y = f2bf(pv[1]);
            u0.z = f2bf(pv[2]); u0.w = f2bf(pv[3]);
            u1.x = f2bf(pv[4]); u1.y = f2bf(pv[5]);
            u1.z = f2bf(pv[6]); u1.w = f2bf(pv[7]);
            *(ushort4*)&pb[ti * PR + 4 * lane]       = u0;
            *(ushort4*)&pb[ti * PR + 256 + 4 * lane] = u1;
        }
    };

    // Prologue: stage chunk 0.
    PROCESS(0);
    __syncthreads();

    for (int c = 0; c < NCH; ++c) {
        // 1) Issue ALL 16 Whf fragment loads for this chunk (oldest vmem),
        //    pin them register-resident, fence.
        const unsigned short* wBc = wAll + (size_t)c * (64 * 128);
        bf16x8 br[16];
#pragma unroll
        for (int ks = 0; ks < CH / 32; ++ks)
            br[ks] = *(const bf16x8*)&wBc[ks * 512];
#pragma unroll
        for (int ks = 0; ks < CH / 32; ++ks)
            asm volatile("" : "+v"(br[ks]));
        __builtin_amdgcn_sched_barrier(0);

        // 2) Produce next chunk's P (other buffer) while br is in flight,
        //    or finalize row sums on the last chunk.
        if (c + 1 < NCH) {
            PROCESS(c + 1);
        } else {
#pragma unroll
            for (int rr = 0; rr < 4; ++rr) {
                float s = s_run[rr];
#pragma unroll
                for (int o = 32; o; o >>= 1) s += __shfl_xor(s, o);
                if (lane == 0) rsum[wave * 4 + rr] = s;
            }
        }
        __builtin_amdgcn_sched_barrier(0);

        // 3) MFMA phase: ds_read A-frags; br already register-resident.
        const unsigned short* pA0 = &p[c & 1][l16 * PR];
        const unsigned short* pA1 = &p[c & 1][(16 + l16) * PR];
#pragma unroll
        for (int ks = 0; ks < CH / 32; ++ks) {
            bf16x8 afr0 = *(const bf16x8*)&pA0[ks * 32 + quad * 8];
            bf16x8 afr1 = *(const bf16x8*)&pA1[ks * 32 + quad * 8];
            acc0 = __builtin_amdgcn_mfma_f32_16x16x32_bf16(afr0, br[ks], acc0,
                                                           0, 0, 0);
            acc1 = __builtin_amdgcn_mfma_f32_16x16x32_bf16(afr1, br[ks], acc1,
                                                           0, 0, 0);
        }
        __syncthreads();
    }

    // ---- Epilogue: /rowsum, ELU, store (row m, col = wave*16 + l16) ----
#pragma unroll
    for (int t = 0; t < 2; ++t) {
        const f32x4 accT = t ? acc1 : acc0;
#pragma unroll
        for (int r = 0; r < 4; ++r) {
            const int m = t * 16 + quad * 4 + r;
            const float inv = 1.f / rsum[m];
            float v = accT[r] * inv;
            v = (v > 0.f) ? v : expm1f(v);
            out[((size_t)b * N_ + i0 + m) * FOUT + wave * 16 + l16] = v;
        }
    }
}

// ---------------------------------------------------------------------------
extern "C" void kernel_launch(void* const* d_in, const int* in_sizes, int n_in,
                              void* d_out, int out_size, void* d_ws, size_t ws_size,
                              hipStream_t stream) {
    const float* x   = (const float*)d_in[0];
    const int*   adj = (const int*)d_in[1];
    const float* W   = (const float*)d_in[2];
    const float* a   = (const float*)d_in[3];
    float* out = (float*)d_out;

    // ws: Whf bf16 (4 MB) | Wt bf16 (64 KB) | f1 (64 KB) | f2 (64 KB)
    //   | maskW (4 MB)
    unsigned short* Whf = (unsigned short*)d_ws;
    unsigned short* Wt  = Whf + (size_t)B_ * FOUT * N_;
    float* f1 = (float*)(Wt + (size_t)FOUT * FIN);
    float* f2 = f1 + (size_t)B_ * N_;
    unsigned long long* maskW = (unsigned long long*)(f2 + (size_t)B_ * N_);

    hipLaunchKernelGGL(k0_wt, dim3(FOUT), dim3(FIN), 0, stream, W, Wt);
    hipLaunchKernelGGL(kf_ka_pack, dim3(512 + 2048), dim3(256), 0, stream,
                       x, Wt, a, adj, Whf, f1, f2, maskW);
    hipLaunchKernelGGL(kb_attn, dim3(B_ * N_ / KR), dim3(512), 0, stream,
                       maskW, Whf, f1, f2, out);
}

// Round 12
// 230.864 us; speedup vs baseline: 1.1871x; 1.1871x over previous
//
#include <hip/hip_runtime.h>
#include <hip/hip_bf16.h>
#include <math.h>

constexpr int B_   = 8;
constexpr int N_   = 2048;
constexpr int FIN  = 256;
constexpr int FOUT = 128;

constexpr int CH  = 512;          // KB K-chunk length
constexpr int NCH = N_ / CH;      // 4 chunks
constexpr int PR  = 520;          // 16B-aligned row stride (1040 B); R8 showed
                                  // non-multiple-of-8 pad splits ds_read_b128
constexpr int KR  = 32;          // kb rows per block (R9 win: halves Whf L2)
constexpr int XR  = FIN + 8;      // 264 shorts per xs row (pad)
constexpr int TR  = 40;           // ka transpose-tile row stride (32 j + 8 pad)

typedef __attribute__((ext_vector_type(8))) short bf16x8;
typedef __attribute__((ext_vector_type(4))) float f32x4;
typedef __attribute__((ext_vector_type(4))) int   i32x4;

static __device__ __forceinline__ unsigned short f2bf(float f) {
    __hip_bfloat16 h = __float2bfloat16(f);
    return *reinterpret_cast<unsigned short*>(&h);
}
static __device__ __forceinline__ i32x4 ntload4(const int* p) {
    return __builtin_nontemporal_load((const i32x4*)p);
}

// ---------------------------------------------------------------------------
// K0: Wt[n][k] = bf16(W[k][n])  (dim-major weight, 64 KB). Tiny (~3 us).
// ---------------------------------------------------------------------------
__global__ __launch_bounds__(256) void k0_wt(const float* __restrict__ W,
                                             unsigned short* __restrict__ Wt) {
    Wt[blockIdx.x * FIN + threadIdx.x] = f2bf(W[threadIdx.x * FOUT + blockIdx.x]);
}

// ---------------------------------------------------------------------------
// KF: fused ka (Wh GEMM -> fragment-major Whf + f1/f2) AND adj->bitmask pack
// via block-role split (R7; at its ~210 MB HBM roofline, ~31 us). UNCHANGED.
// ---------------------------------------------------------------------------
__global__ __launch_bounds__(256) void kf_ka_pack(
        const float* __restrict__ x,
        const unsigned short* __restrict__ Wt,
        const float* __restrict__ a,
        const int* __restrict__ adj,
        unsigned short* __restrict__ Whf,
        float* __restrict__ f1,
        float* __restrict__ f2,
        unsigned long long* __restrict__ maskW) {
    __shared__ unsigned short xs[32 * XR];   // 16.5 KB; reused as T[128][TR]
    __shared__ float as[2 * FOUT];           // 1 KB
    __shared__ float fred[2][4][32];         // 1 KB

    const int beta = blockIdx.x;
    const int tid  = threadIdx.x;

    if (beta % 5 != 0) {
        // ================= pack role (2048 blocks) =================
        // bit l of maskW[4g+q] = (adj[256g + 4l + q] > 0)   (verified R4+)
        const int pid  = beta - beta / 5 - 1;       // 0..2047
        const int lane = tid & 63, wv = tid >> 6;
        const int gbase = pid * 64 + wv * 16;       // 131072 groups total
        for (int t0 = 0; t0 < 16; t0 += 4) {
            i32x4 vv[4];
#pragma unroll
            for (int u = 0; u < 4; ++u)
                vv[u] = ntload4(adj + (size_t)(gbase + t0 + u) * 256 + 4 * lane);
#pragma unroll
            for (int u = 0; u < 4; ++u) {
                const int g = gbase + t0 + u;
                unsigned long long b0 = __ballot(vv[u][0] > 0);
                unsigned long long b1 = __ballot(vv[u][1] > 0);
                unsigned long long b2 = __ballot(vv[u][2] > 0);
                unsigned long long b3 = __ballot(vv[u][3] > 0);
                if (lane < 4) {
                    unsigned long long w = (lane == 0) ? b0
                                         : (lane == 1) ? b1
                                         : (lane == 2) ? b2 : b3;
                    maskW[(size_t)4 * g + lane] = w;
                }
            }
        }
        return;
    }

    // ================= ka role (512 blocks) =================
    // Whf fragment-major: element (d = nt*16+n16, k = K8*8+j) at
    // ((b*8+nt)*256 + K8)*128 + n16*8 + j   (verified R5+).
    const int j0 = (beta / 5) * 32;          // global flat row base
    const int b  = j0 >> 11;
    const int jb = j0 & (N_ - 1);

    if (tid < 2 * FOUT) as[tid] = a[tid];
    {   // stage 32 x-rows (fp32 -> bf16), coalesced 32 KB read
        const float4* xsrc = (const float4*)(x + (size_t)j0 * FIN);
#pragma unroll
        for (int t = 0; t < 8; ++t) {
            const int idx = tid + t * 256;
            float4 v = xsrc[idx];
            const int row = idx >> 6, c4 = idx & 63;
            ushort4 u;
            u.x = f2bf(v.x); u.y = f2bf(v.y); u.z = f2bf(v.z); u.w = f2bf(v.w);
            *(ushort4*)&xs[row * XR + c4 * 4] = u;
        }
    }
    __syncthreads();

    const int wave = tid >> 6, lane = tid & 63;
    const int quad = lane >> 4, l16 = lane & 15;

    f32x4 acc[2][2];  // [a-tile(d)][n-tile(j)]
#pragma unroll
    for (int aa = 0; aa < 2; ++aa)
#pragma unroll
        for (int nn = 0; nn < 2; ++nn) acc[aa][nn] = {0.f, 0.f, 0.f, 0.f};

    const unsigned short* wtA0 = Wt + (size_t)(32 * wave + l16) * FIN;
    const unsigned short* wtA1 = wtA0 + 16 * FIN;
#pragma unroll
    for (int ks = 0; ks < FIN / 32; ++ks) {
        const int kof = ks * 32 + quad * 8;
        bf16x8 af0 = *(const bf16x8*)&wtA0[kof];
        bf16x8 af1 = *(const bf16x8*)&wtA1[kof];
        bf16x8 bf0 = *(const bf16x8*)&xs[l16 * XR + kof];
        bf16x8 bf1 = *(const bf16x8*)&xs[(16 + l16) * XR + kof];
        acc[0][0] = __builtin_amdgcn_mfma_f32_16x16x32_bf16(af0, bf0, acc[0][0], 0, 0, 0);
        acc[0][1] = __builtin_amdgcn_mfma_f32_16x16x32_bf16(af0, bf1, acc[0][1], 0, 0, 0);
        acc[1][0] = __builtin_amdgcn_mfma_f32_16x16x32_bf16(af1, bf0, acc[1][0], 0, 0, 0);
        acc[1][1] = __builtin_amdgcn_mfma_f32_16x16x32_bf16(af1, bf1, acc[1][1], 0, 0, 0);
    }
    __syncthreads();   // xs dead; safe to reuse as transpose tile T

    unsigned short* T = xs;   // [128][TR]
    float pf[2][2] = {{0.f, 0.f}, {0.f, 0.f}};  // [f1/f2][n-tile]
#pragma unroll
    for (int aa = 0; aa < 2; ++aa)
#pragma unroll
        for (int nn = 0; nn < 2; ++nn)
#pragma unroll
            for (int r = 0; r < 4; ++r) {
                const int d = 32 * wave + 16 * aa + 4 * quad + r;
                const float v = acc[aa][nn][r];
                T[d * TR + nn * 16 + l16] = f2bf(v);
                pf[0][nn] += v * as[d];
                pf[1][nn] += v * as[FOUT + d];
            }
#pragma unroll
    for (int ff = 0; ff < 2; ++ff)
#pragma unroll
        for (int nn = 0; nn < 2; ++nn) {
            float v = pf[ff][nn];
            v += __shfl_xor(v, 16);
            v += __shfl_xor(v, 32);
            pf[ff][nn] = v;
        }
    if (quad == 0) {
#pragma unroll
        for (int ff = 0; ff < 2; ++ff)
#pragma unroll
            for (int nn = 0; nn < 2; ++nn)
                fred[ff][wave][nn * 16 + l16] = pf[ff][nn];
    }
    __syncthreads();

    // ---- Epilogue: write fragment-major Whf from the T tile ----
    unsigned short* dstW = Whf + (size_t)(b * 8) * 256 * 128;  // batch base
    const int jb8 = jb >> 3;
#pragma unroll
    for (int it = 0; it < 2; ++it) {
        const int i   = it * 256 + tid;
        const int n16 = i & 15, q = (i >> 4) & 3, nt = i >> 6;
        bf16x8 v = *(const bf16x8*)&T[(nt * 16 + n16) * TR + q * 8];
        *(bf16x8*)&dstW[((size_t)nt * 256 + jb8 + q) * 128 + n16 * 8] = v;
    }
    if (tid < 64) {
        const int ff = tid >> 5, j32 = tid & 31;
        const float s = fred[ff][0][j32] + fred[ff][1][j32] +
                        fred[ff][2][j32] + fred[ff][3][j32];
        (ff ? f2 : f1)[(size_t)b * N_ + jb + j32] = s;
    }
}

// ---------------------------------------------------------------------------
// KB: fused masked softmax + P@Wh (MFMA) + ELU.
// R12 = R9-EXACT (the session best, 231.6 us). R11's forced br[16] prefetch
// spilled (64 pinned VGPRs + PROCESS state > 128 cap; pins forbade
// re-sinking) -> -42 us, same signature as R8. Scheduling interventions are
// 0-for-4 on this kernel (R1/R3: null; R8/R11: spill); every win was a
// traffic-shape change (R5 layout, R9 KR=32, R4 mask). Locking in R9.
// ---------------------------------------------------------------------------
__global__ __launch_bounds__(512, 4) void kb_attn(const unsigned long long* __restrict__ maskW,
                                                  const unsigned short* __restrict__ Whf,
                                                  const float* __restrict__ f1,
                                                  const float* __restrict__ f2,
                                                  float* __restrict__ out) {
    __shared__ unsigned short p[2][KR * PR];  // 66.6 KB
    __shared__ float rsum[KR];

    const int tid  = threadIdx.x;
    const int b    = blockIdx.x & 7;          // XCD-pinned batch
    const int i0   = (blockIdx.x >> 3) * KR;  // 32-row tile
    const int wave = tid >> 6, lane = tid & 63;  // wave 0..7
    const int quad = lane >> 4, l16 = lane & 15;

    const f32x4* f2b4 = (const f32x4*)(f2 + (size_t)b * N_);

    float f1r[4], s_run[4];
#pragma unroll
    for (int rr = 0; rr < 4; ++rr) {
        f1r[rr]   = f1[(size_t)b * N_ + i0 + wave * 4 + rr];
        s_run[rr] = 0.f;
    }

    f32x4 acc0 = {0.f, 0.f, 0.f, 0.f};   // rows  0..15 of the tile
    f32x4 acc1 = {0.f, 0.f, 0.f, 0.f};   // rows 16..31 of the tile
    // fragment-major base for this wave's n-tile (nt = wave):
    // element (c,ks): offset = ((b*8+wave)*256 + c*64 + ks*4 + quad)*128
    //                          + l16*8
    const unsigned short* wAll =
        Whf + ((size_t)(b * 8 + wave) * 256) * 128 + quad * 128 + l16 * 8;

    // Consume chunk c: leaky-relu, mask-by-bit, exp, rowsum, pack->LDS.
    auto PROCESS = [&](int c) {
        unsigned short* pb = &p[c & 1][0];
        const f32x4 fva = f2b4[c * (CH / 4) + lane];
        const f32x4 fvb = f2b4[c * (CH / 4) + 64 + lane];
#pragma unroll
        for (int rr = 0; rr < 4; ++rr) {
            const int ti = wave * 4 + rr;
            const float f1i = f1r[rr];
            const size_t gbase =
                (((size_t)b * N_ + (size_t)(i0 + ti)) * N_ + (size_t)c * CH) >> 8;
            const unsigned long long* mw = maskW + 4 * gbase;   // wave-uniform
            const unsigned long long m00 = mw[0], m01 = mw[1];
            const unsigned long long m02 = mw[2], m03 = mw[3];
            const unsigned long long m10 = mw[4], m11 = mw[5];
            const unsigned long long m12 = mw[6], m13 = mw[7];

            float e[8];
            e[0] = f1i + fva[0]; e[1] = f1i + fva[1];
            e[2] = f1i + fva[2]; e[3] = f1i + fva[3];
            e[4] = f1i + fvb[0]; e[5] = f1i + fvb[1];
            e[6] = f1i + fvb[2]; e[7] = f1i + fvb[3];
#pragma unroll
            for (int q = 0; q < 8; ++q) e[q] = (e[q] >= 0.f) ? e[q] : 2.f * e[q];

            float pv[8];
            pv[0] = ((m00 >> lane) & 1ull) ? __expf(e[0]) : 0.f;
            pv[1] = ((m01 >> lane) & 1ull) ? __expf(e[1]) : 0.f;
            pv[2] = ((m02 >> lane) & 1ull) ? __expf(e[2]) : 0.f;
            pv[3] = ((m03 >> lane) & 1ull) ? __expf(e[3]) : 0.f;
            pv[4] = ((m10 >> lane) & 1ull) ? __expf(e[4]) : 0.f;
            pv[5] = ((m11 >> lane) & 1ull) ? __expf(e[5]) : 0.f;
            pv[6] = ((m12 >> lane) & 1ull) ? __expf(e[6]) : 0.f;
            pv[7] = ((m13 >> lane) & 1ull) ? __expf(e[7]) : 0.f;

            s_run[rr] += ((pv[0] + pv[1]) + (pv[2] + pv[3])) +
                         ((pv[4] + pv[5]) + (pv[6] + pv[7]));

            ushort4 u0, u1;
            u0.x = f2bf(pv[0]); u0.y = f2bf(pv[1]);
            u0.z = f2bf(pv[2]); u0.w = f2bf(pv[3]);
            u1.x = f2bf(pv[4]); u1.y = f2bf(pv[5]);
            u1.z = f2bf(pv[6]); u1.w = f2bf(pv[7]);
            *(ushort4*)&pb[ti * PR + 4 * lane]       = u0;
            *(ushort4*)&pb[ti * PR + 256 + 4 * lane] = u1;
        }
    };

    // Prologue: stage chunk 0.
    PROCESS(0);
    __syncthreads();

    for (int c = 0; c < NCH; ++c) {
        // Produce next chunk's P (other buffer), or finalize row sums.
        if (c + 1 < NCH) {
            PROCESS(c + 1);
        } else {
#pragma unroll
            for (int rr = 0; rr < 4; ++rr) {
                float s = s_run[rr];
#pragma unroll
                for (int o = 32; o; o >>= 1) s += __shfl_xor(s, o);
                if (lane == 0) rsum[wave * 4 + rr] = s;
            }
        }

        // MFMA phase: each B-fragment feeds BOTH row-tiles (in-reg reuse x2).
        const unsigned short* wBc = wAll + (size_t)c * (64 * 128);
        const unsigned short* pA0 = &p[c & 1][l16 * PR];
        const unsigned short* pA1 = &p[c & 1][(16 + l16) * PR];
#pragma unroll
        for (int ks = 0; ks < CH / 32; ++ks) {
            bf16x8 bfr  = *(const bf16x8*)&wBc[ks * 512];
            bf16x8 afr0 = *(const bf16x8*)&pA0[ks * 32 + quad * 8];
            bf16x8 afr1 = *(const bf16x8*)&pA1[ks * 32 + quad * 8];
            acc0 = __builtin_amdgcn_mfma_f32_16x16x32_bf16(afr0, bfr, acc0,
                                                           0, 0, 0);
            acc1 = __builtin_amdgcn_mfma_f32_16x16x32_bf16(afr1, bfr, acc1,
                                                           0, 0, 0);
        }
        __syncthreads();
    }

    // ---- Epilogue: /rowsum, ELU, store (row m, col = wave*16 + l16) ----
#pragma unroll
    for (int t = 0; t < 2; ++t) {
        const f32x4 accT = t ? acc1 : acc0;
#pragma unroll
        for (int r = 0; r < 4; ++r) {
            const int m = t * 16 + quad * 4 + r;
            const float inv = 1.f / rsum[m];
            float v = accT[r] * inv;
            v = (v > 0.f) ? v : expm1f(v);
            out[((size_t)b * N_ + i0 + m) * FOUT + wave * 16 + l16] = v;
        }
    }
}

// ---------------------------------------------------------------------------
extern "C" void kernel_launch(void* const* d_in, const int* in_sizes, int n_in,
                              void* d_out, int out_size, void* d_ws, size_t ws_size,
                              hipStream_t stream) {
    const float* x   = (const float*)d_in[0];
    const int*   adj = (const int*)d_in[1];
    const float* W   = (const float*)d_in[2];
    const float* a   = (const float*)d_in[3];
    float* out = (float*)d_out;

    // ws: Whf bf16 (4 MB) | Wt bf16 (64 KB) | f1 (64 KB) | f2 (64 KB)
    //   | maskW (4 MB)
    unsigned short* Whf = (unsigned short*)d_ws;
    unsigned short* Wt  = Whf + (size_t)B_ * FOUT * N_;
    float* f1 = (float*)(Wt + (size_t)FOUT * FIN);
    float* f2 = f1 + (size_t)B_ * N_;
    unsigned long long* maskW = (unsigned long long*)(f2 + (size_t)B_ * N_);

    hipLaunchKernelGGL(k0_wt, dim3(FOUT), dim3(FIN), 0, stream, W, Wt);
    hipLaunchKernelGGL(kf_ka_pack, dim3(512 + 2048), dim3(256), 0, stream,
                       x, Wt, a, adj, Whf, f1, f2, maskW);
    hipLaunchKernelGGL(kb_attn, dim3(B_ * N_ / KR), dim3(512), 0, stream,
                       maskW, Whf, f1, f2, out);
}